// Round 12
// baseline (400.097 us; speedup 1.0000x reference)
//
#include <hip/hip_runtime.h>

typedef unsigned short ushort_t;
typedef unsigned int u32;
typedef _Float16 f16;
typedef f16 f16x8 __attribute__((ext_vector_type(8)));
typedef f16 f16x2 __attribute__((ext_vector_type(2)));
typedef ushort_t u16x8 __attribute__((ext_vector_type(8)));
typedef float f32x4 __attribute__((ext_vector_type(4)));

#define C_DIM 256
#define HW 4096
#define CHW (C_DIM*HW)
#define L2E 1.4426950408889634f

// Device-global scratch. Internal pipeline f16.
__device__ __align__(16) f16 g_xbT[4 * CHW];
__device__ __align__(16) f16 g_q[4 * CHW];
__device__ __align__(16) f16 g_k[4 * CHW];
__device__ __align__(16) f16 g_v[4 * CHW];
__device__ __align__(16) f16 g_opart[16 * CHW];   // [slot=jq*4+n][c][i] normalized O^T
__device__ float g_ml[16 * 2 * HW];               // [slot][{m,l}][i]
__device__ int g_mode[1];   // 0 = inputs bf16, 1 = inputs f32

__device__ __forceinline__ float bf2f(ushort_t h) {
    union { u32 u; float f; } v; v.u = ((u32)h) << 16; return v.f;
}
__device__ __forceinline__ ushort_t f2bf(float f) {
    union { float f; u32 u; } v; v.f = f;
    u32 r = v.u + 0x7FFF + ((v.u >> 16) & 1);
    return (ushort_t)(r >> 16);
}
__device__ __forceinline__ float fin0(float v) {
    return (v > -1e30f && v < 1e30f) ? v : 0.f;
}
__device__ __forceinline__ f16 sf16(float v) {
    return (f16)((v > -1e4f && v < 1e4f) ? v : 0.f);
}
__device__ __forceinline__ void gl2lds16(const f16* g, f16* l) {
    __builtin_amdgcn_global_load_lds(
        (const __attribute__((address_space(1))) u32*)g,
        (__attribute__((address_space(3))) u32*)l, 16, 0, 0);
}

// ---------------- kernel 0: dtype probe ----------------
__global__ void k_probe(const void* __restrict__ xv) {
    const ushort_t* xh = (const ushort_t*)xv;
    int lane = threadIdx.x;
    float s = 0.f;
    for (int i = lane; i < 2048; i += 64) {
        float v = fabsf(bf2f(xh[i]));
        v = (v < 1e6f) ? v : 1e6f;
        s += v;
    }
#pragma unroll
    for (int d = 1; d < 64; d <<= 1) s += __shfl_xor(s, d, 64);
    if (lane == 0) g_mode[0] = (s * (1.f / 2048.f) > 100.f) ? 1 : 0;
}

__global__ void k_sentinel(ushort_t* out, int n) {
    int i = blockIdx.x * 256 + threadIdx.x;
    if (i < n) out[i] = f2bf(777.f);
}

// ---------------- kernel 1: x (N,C,HW) -> g_xbT f16 (N,HW,C) ----------------
__global__ __launch_bounds__(256) void k_transpose(const void* __restrict__ xv) {
    __shared__ f16 t[64][66];
    int mode = g_mode[0];
    int n = blockIdx.z, c0 = blockIdx.y * 64, l0 = blockIdx.x * 64;
    int tid = threadIdx.x;
    f16* ob = g_xbT + n * CHW;
    int lq = (tid & 15) * 4;
    int cl = tid >> 4;
    if (mode == 0) {
        const ushort_t* xb = (const ushort_t*)xv + n * CHW;
#pragma unroll
        for (int p = 0; p < 4; ++p) {
            int c = cl + 16 * p;
            ushort4 v = *(const ushort4*)(xb + (c0 + c) * HW + l0 + lq);
            t[lq + 0][c] = sf16(bf2f(v.x));
            t[lq + 1][c] = sf16(bf2f(v.y));
            t[lq + 2][c] = sf16(bf2f(v.z));
            t[lq + 3][c] = sf16(bf2f(v.w));
        }
    } else {
        const float* xb = (const float*)xv + n * CHW;
#pragma unroll
        for (int p = 0; p < 4; ++p) {
            int c = cl + 16 * p;
            float4 v = *(const float4*)(xb + (c0 + c) * HW + l0 + lq);
            t[lq + 0][c] = sf16(v.x);
            t[lq + 1][c] = sf16(v.y);
            t[lq + 2][c] = sf16(v.z);
            t[lq + 3][c] = sf16(v.w);
        }
    }
    __syncthreads();
    int c2 = (tid & 31) * 2;
    int lr = tid >> 5;
#pragma unroll
    for (int p = 0; p < 8; ++p) {
        int l = lr + 8 * p;
        u32 pair = *(const u32*)&t[l][c2];
        *(u32*)(ob + (l0 + l) * C_DIM + c0 + c2) = pair;
    }
}

// ---------------- kernel 2: projections (f16 MFMA) ----------------
__global__ __launch_bounds__(256) void k_proj(
    const void* __restrict__ Wq, const void* __restrict__ bq,
    const void* __restrict__ Wk, const void* __restrict__ bk,
    const void* __restrict__ Wv, const void* __restrict__ bv)
{
    __shared__ __align__(16) f16 lds_x[128 * 64];
    __shared__ __align__(16) f16 lds_w[128 * 64];
    int mode = g_mode[0];
    int l0 = blockIdx.x * 128;
    int og0 = blockIdx.y * 128;
    int n = blockIdx.z;
    int mat = og0 >> 8;       // 0=q,1=k,2=v
    int om0 = og0 & 255;
    const void* W = (mat == 0) ? Wq : (mat == 1) ? Wk : Wv;
    const void* bias = (mat == 0) ? bq : (mat == 1) ? bk : bv;
    int tid = threadIdx.x, w = tid >> 6, lane = tid & 63;
    int quad = lane >> 4, l16 = lane & 15;
    const f16* xb = g_xbT + n * CHW;

    f32x4 acc[2][8];
#pragma unroll
    for (int a = 0; a < 2; a++)
#pragma unroll
        for (int b = 0; b < 8; b++) acc[a][b] = f32x4{0.f, 0.f, 0.f, 0.f};

    for (int ch = 0; ch < 4; ++ch) {
        int cc0 = ch * 64;
        f16x8 xs[4], wsr[4];
#pragma unroll
        for (int ti = 0; ti < 4; ++ti) {
            int s = (w * 4 + ti) * 64 + lane;
            int row = s >> 3, gp = s & 7;
            xs[ti] = *(const f16x8*)(xb + (l0 + row) * C_DIM + cc0 + gp * 8);
            f16x8 h;
            if (mode == 0) {
                u16x8 wv = *(const u16x8*)((const ushort_t*)W + (om0 + row) * C_DIM + cc0 + gp * 8);
#pragma unroll
                for (int e = 0; e < 8; e++) h[e] = sf16(bf2f(wv[e]));
            } else {
                const float* wf = (const float*)W + (om0 + row) * C_DIM + cc0 + gp * 8;
#pragma unroll
                for (int e = 0; e < 8; e++) h[e] = sf16(wf[e]);
            }
            wsr[ti] = h;
        }
        __syncthreads();
#pragma unroll
        for (int ti = 0; ti < 4; ++ti) {
            int s = (w * 4 + ti) * 64 + lane;
            int row = s >> 3, gp = s & 7;
            int pos = gp ^ (row & 7);
            *(f16x8*)(lds_x + (row * 8 + pos) * 8) = xs[ti];
            *(f16x8*)(lds_w + (row * 8 + pos) * 8) = wsr[ti];
        }
        __syncthreads();
#pragma unroll
        for (int ks = 0; ks < 2; ++ks) {
            f16x8 af[2];
#pragma unroll
            for (int mt = 0; mt < 2; ++mt) {
                int row = w * 32 + mt * 16 + l16;
                int g = ks * 4 + quad;
                int pos = g ^ (row & 7);
                af[mt] = *(const f16x8*)(lds_x + (row * 8 + pos) * 8);
            }
#pragma unroll
            for (int nt = 0; nt < 8; ++nt) {
                int rowo = nt * 16 + l16;
                int g = ks * 4 + quad;
                int pos = g ^ (rowo & 7);
                f16x8 bfv = *(const f16x8*)(lds_w + (rowo * 8 + pos) * 8);
                if (mat < 2) {
                    acc[0][nt] = __builtin_amdgcn_mfma_f32_16x16x32_f16(af[0], bfv, acc[0][nt], 0, 0, 0);
                    acc[1][nt] = __builtin_amdgcn_mfma_f32_16x16x32_f16(af[1], bfv, acc[1][nt], 0, 0, 0);
                } else {
                    acc[0][nt] = __builtin_amdgcn_mfma_f32_16x16x32_f16(bfv, af[0], acc[0][nt], 0, 0, 0);
                    acc[1][nt] = __builtin_amdgcn_mfma_f32_16x16x32_f16(bfv, af[1], acc[1][nt], 0, 0, 0);
                }
            }
        }
        __syncthreads();
    }

    auto loadb = [&](int i) -> float {
        return mode ? ((const float*)bias)[i] : bf2f(((const ushort_t*)bias)[i]);
    };
    if (mat < 2) {
        f16* T = ((mat == 0) ? g_q : g_k) + n * CHW;
        float bvv[8];
#pragma unroll
        for (int nt = 0; nt < 8; nt++) bvv[nt] = loadb(om0 + nt * 16 + l16);
#pragma unroll
        for (int mt = 0; mt < 2; mt++)
#pragma unroll
            for (int nt = 0; nt < 8; nt++)
#pragma unroll
                for (int r = 0; r < 4; r++) {
                    int l = l0 + w * 32 + mt * 16 + quad * 4 + r;
                    int o = om0 + nt * 16 + l16;
                    T[l * C_DIM + o] = sf16(acc[mt][nt][r] + bvv[nt]);
                }
    } else {
        f16* T = g_v + n * CHW;
#pragma unroll
        for (int mt = 0; mt < 2; mt++)
#pragma unroll
            for (int nt = 0; nt < 8; nt++)
#pragma unroll
                for (int r = 0; r < 4; r++) {
                    int o = om0 + nt * 16 + quad * 4 + r;
                    int l = l0 + w * 32 + mt * 16 + l16;
                    T[o * HW + l] = sf16(acc[mt][nt][r] + loadb(o));
                }
    }
}

// ---------------- kernel 3: flash attention, S^T, BM=128, split-j x4, deferred PV ----------------
// Pipeline invariant at iter it entry: vbuf = V(it-1), vreg = V(it), kbuf[buf] = K(it).
// Order: S(it); PV(it-1) from vbuf; barrier; writeV (vbuf<-V(it)); loadV(it+1);
// softmax(it); rescale; P(it)->pfrag; barrier.
__global__ __launch_bounds__(256, 2) void k_attn() {
    __shared__ __align__(16) char smem[59392];
    f16* kbuf = (f16*)smem;             // 2 x 8192 f16 (32 j x 32 granules, swizzled)
    f16* vbuf = (f16*)(smem + 32768);   // 8192 f16 (256 c x 4 granules, swizzled)
    f16* pb   = (f16*)(smem + 49152);   // 4 waves x 2 mt x 16 i x 40 f16

    int bid = blockIdx.x;
    int x8 = bid & 7;
    int n = x8 >> 1, jhi = x8 & 1;      // XCD sees fixed (n, j-half)
    int rest = bid >> 3;
    int jlo = rest & 1;
    int i0 = (rest >> 1) * 128;         // 32 i-tiles of BM=128
    int jq = jhi * 2 + jlo;
    int tid = threadIdx.x, w = tid >> 6, lane = tid & 63;
    int quad = lane >> 4, l16 = lane & 15;

    const f16* Qb = g_q + n * CHW;
    const f16* Kb = g_k + n * CHW;
    const f16* Vb = g_v + n * CHW;
    f16* pw = pb + w * 1280;

    // Absolute LDS read addresses for both K buffers
    const f16* kaddr[2][16];   // [buf][kk*2 + jtile]
    const f16* vaddr[16];
#pragma unroll
    for (int kk = 0; kk < 8; kk++) {
        int g2 = kk * 4 + quad;
        int pos = (g2 & 24) | ((g2 & 7) ^ (l16 & 7));
#pragma unroll
        for (int b = 0; b < 2; b++) {
            kaddr[b][kk * 2 + 0] = kbuf + b * 8192 + (l16 * 32 + pos) * 8;
            kaddr[b][kk * 2 + 1] = kbuf + b * 8192 + ((16 + l16) * 32 + pos) * 8;
        }
    }
#pragma unroll
    for (int ct = 0; ct < 16; ct++) {
        int c = ct * 16 + l16;
        vaddr[ct] = vbuf + (c * 4 + (quad ^ ((c >> 1) & 3))) * 8;
    }

    // Q fragments (B-operand), 2 i-groups of 16 per wave
    f16x8 qf[2][8];
#pragma unroll
    for (int mt = 0; mt < 2; mt++) {
        const f16* qrow = Qb + (i0 + w * 32 + mt * 16 + l16) * C_DIM + quad * 8;
#pragma unroll
        for (int kk = 0; kk < 8; kk++)
            qf[mt][kk] = *(const f16x8*)(qrow + kk * 32);
    }

    f32x4 o_acc[2][16];
#pragma unroll
    for (int mt = 0; mt < 2; mt++)
#pragma unroll
        for (int i = 0; i < 16; i++) o_acc[mt][i] = f32x4{0.f, 0.f, 0.f, 0.f};
    float m_[2] = {-1e30f, -1e30f}, l_[2] = {0.f, 0.f};
    f16x8 pf0 = {0, 0, 0, 0, 0, 0, 0, 0};   // deferred P (zero: iter0 PV adds 0 x finite V(0))
    f16x8 pf1 = {0, 0, 0, 0, 0, 0, 0, 0};

    auto stageK = [&](int jt, int buf) {
#pragma unroll
        for (int s = 0; s < 4; ++s) {
            int idx = s * 256 + tid;
            int j = idx >> 5, gp = idx & 31;
            int gg = (gp & 24) | ((gp & 7) ^ (j & 7));
            gl2lds16(Kb + (jt * 32 + j) * C_DIM + gg * 8,
                     kbuf + (buf * 1024 + s * 256 + w * 64) * 8);
        }
    };
    f16x8 vreg[4];
    int vgoff[4], vloff[4];
#pragma unroll
    for (int s = 0; s < 4; ++s) {
        int idx = s * 256 + tid;
        int c = idx >> 2, jp = idx & 3;
        int jg = jp ^ ((c >> 1) & 3);
        vgoff[s] = c * HW + jg * 8;
        vloff[s] = idx * 8;
    }
    auto loadV = [&](int jt) {
#pragma unroll
        for (int s = 0; s < 4; ++s)
            vreg[s] = *(const f16x8*)(Vb + vgoff[s] + jt * 32);
    };
    auto writeV = [&]() {
#pragma unroll
        for (int s = 0; s < 4; ++s)
            *(f16x8*)(vbuf + vloff[s]) = vreg[s];
    };

    int jt0 = jq * 32;
    stageK(jt0, 0);
    loadV(jt0);      // vreg = V(0)
    writeV();        // vbuf = V(0)  (iter0 deferred PV reads finite data, P=0)
    __syncthreads();

    for (int it = 0; it < 32; ++it) {
        int buf = it & 1;
        if (it + 1 < 32) stageK(jt0 + it + 1, buf ^ 1);  // async into other K buffer

        // ---- S^T(it) = K Q^T ----
        f32x4 st[2][2];
        st[0][0] = f32x4{0.f,0.f,0.f,0.f}; st[0][1] = f32x4{0.f,0.f,0.f,0.f};
        st[1][0] = f32x4{0.f,0.f,0.f,0.f}; st[1][1] = f32x4{0.f,0.f,0.f,0.f};
#pragma unroll
        for (int kk = 0; kk < 8; kk++) {
            f16x8 kf0 = *(const f16x8*)kaddr[buf][kk * 2 + 0];
            f16x8 kf1 = *(const f16x8*)kaddr[buf][kk * 2 + 1];
            st[0][0] = __builtin_amdgcn_mfma_f32_16x16x32_f16(kf0, qf[0][kk], st[0][0], 0, 0, 0);
            st[0][1] = __builtin_amdgcn_mfma_f32_16x16x32_f16(kf1, qf[0][kk], st[0][1], 0, 0, 0);
            st[1][0] = __builtin_amdgcn_mfma_f32_16x16x32_f16(kf0, qf[1][kk], st[1][0], 0, 0, 0);
            st[1][1] = __builtin_amdgcn_mfma_f32_16x16x32_f16(kf1, qf[1][kk], st[1][1], 0, 0, 0);
        }

        // ---- deferred O^T += V(it-1) P^T(it-1): vbuf still holds V(it-1) ----
#pragma unroll
        for (int ct = 0; ct < 16; ++ct) {
            f16x8 vf = *(const f16x8*)vaddr[ct];
            o_acc[0][ct] = __builtin_amdgcn_mfma_f32_16x16x32_f16(vf, pf0, o_acc[0][ct], 0, 0, 0);
            o_acc[1][ct] = __builtin_amdgcn_mfma_f32_16x16x32_f16(vf, pf1, o_acc[1][ct], 0, 0, 0);
        }

        __syncthreads();   // all vbuf reads (PV it-1) done; K(it+1) drained
        writeV();          // vbuf <- V(it)
        if (it + 1 < 32) loadV(jt0 + it + 1);   // vreg <- V(it+1)

        // ---- per-lane online softmax (quantized max) ----
        float al[2];
        float pv0[2][4], pv1[2][4];
#pragma unroll
        for (int mt = 0; mt < 2; mt++) {
            float smax = fmaxf(fmaxf(fmaxf(st[mt][0][0], st[mt][0][1]), fmaxf(st[mt][0][2], st[mt][0][3])),
                               fmaxf(fmaxf(st[mt][1][0], st[mt][1][1]), fmaxf(st[mt][1][2], st[mt][1][3])));
            smax = fmaxf(smax, __shfl_xor(smax, 16, 64));
            smax = fmaxf(smax, __shfl_xor(smax, 32, 64));
            float mq = __builtin_ceilf(smax * 0.125f) * 8.f;   // quantized up
            float mn = fmaxf(m_[mt], mq);
            al[mt] = __builtin_amdgcn_exp2f((m_[mt] - mn) * L2E);
            float rs = 0.f;
#pragma unroll
            for (int r = 0; r < 4; r++) {
                pv0[mt][r] = __builtin_amdgcn_exp2f((st[mt][0][r] - mn) * L2E);
                pv1[mt][r] = __builtin_amdgcn_exp2f((st[mt][1][r] - mn) * L2E);
                rs += pv0[mt][r] + pv1[mt][r];
            }
            m_[mt] = mn;
            rs += __shfl_xor(rs, 16, 64);
            rs += __shfl_xor(rs, 32, 64);
            l_[mt] = l_[mt] * al[mt] + rs;
        }
        // rescale AFTER deferred PV (o_acc holds state through it-1 at scale m(it-1))
        if (__any((al[0] < 1.0f) || (al[1] < 1.0f))) {
#pragma unroll
            for (int mt = 0; mt < 2; mt++)
#pragma unroll
                for (int t = 0; t < 16; t++) o_acc[mt][t] *= al[mt];
        }

        // ---- P^T(it) to LDS [i][j], read back as B-frag for next iter's PV ----
#pragma unroll
        for (int mt = 0; mt < 2; mt++) {
            f16* pm = pw + mt * 640 + l16 * 40;
            *(f16x2*)(pm + quad * 4)          = f16x2{(f16)pv0[mt][0], (f16)pv0[mt][1]};
            *(f16x2*)(pm + quad * 4 + 2)      = f16x2{(f16)pv0[mt][2], (f16)pv0[mt][3]};
            *(f16x2*)(pm + 16 + quad * 4)     = f16x2{(f16)pv1[mt][0], (f16)pv1[mt][1]};
            *(f16x2*)(pm + 16 + quad * 4 + 2) = f16x2{(f16)pv1[mt][2], (f16)pv1[mt][3]};
        }
        asm volatile("" ::: "memory");
        pf0 = *(const f16x8*)(pw + l16 * 40 + quad * 8);
        pf1 = *(const f16x8*)(pw + 640 + l16 * 40 + quad * 8);

        __syncthreads();   // vbuf = V(it) visible to all waves for next iter's PV
    }

    // ---- final deferred PV (tile 31): vbuf = V(31) ----
#pragma unroll
    for (int ct = 0; ct < 16; ++ct) {
        f16x8 vf = *(const f16x8*)vaddr[ct];
        o_acc[0][ct] = __builtin_amdgcn_mfma_f32_16x16x32_f16(vf, pf0, o_acc[0][ct], 0, 0, 0);
        o_acc[1][ct] = __builtin_amdgcn_mfma_f32_16x16x32_f16(vf, pf1, o_acc[1][ct], 0, 0, 0);
    }

    // ---- write partials: normalized O^T (f16) + m,l (f32) ----
    int slot = jq * 4 + n;
    if (quad == 0) {
#pragma unroll
        for (int mt = 0; mt < 2; mt++) {
            int i = i0 + w * 32 + mt * 16 + l16;
            g_ml[(slot * 2 + 0) * HW + i] = m_[mt];
            g_ml[(slot * 2 + 1) * HW + i] = l_[mt];
        }
    }
    f16* ob = g_opart + slot * CHW;
#pragma unroll
    for (int mt = 0; mt < 2; mt++) {
        int ig = i0 + w * 32 + mt * 16 + l16;
        float inv = (l_[mt] > 1e-30f) ? 1.0f / l_[mt] : 0.f;
#pragma unroll
        for (int ct = 0; ct < 16; ct++)
#pragma unroll
            for (int r = 0; r < 4; r++) {
                int c = ct * 16 + quad * 4 + r;
                ob[c * HW + ig] = (f16)(o_acc[mt][ct][r] * inv);
            }
    }
}

// ---------------- kernel 4: merge 4 j-quarters + residual + store ----------------
__global__ __launch_bounds__(256) void k_combine(
    const void* __restrict__ xv, const void* __restrict__ gv, void* __restrict__ outv)
{
    int mode = g_mode[0];
    float gam = fin0(mode ? ((const float*)gv)[0] : bf2f(((const ushort_t*)gv)[0]));
    int n = blockIdx.y;
    int base = blockIdx.x * 1024;
#pragma unroll
    for (int e = 0; e < 4; ++e) {
        int off = base + e * 256 + threadIdx.x;
        int i = off & (HW - 1);
        float m = -1e30f;
        float ms[4], ls[4];
#pragma unroll
        for (int s = 0; s < 4; ++s) {
            int slot = s * 4 + n;
            ms[s] = g_ml[(slot * 2 + 0) * HW + i];
            ls[s] = g_ml[(slot * 2 + 1) * HW + i];
            m = fmaxf(m, ms[s]);
        }
        float num = 0.f, den = 0.f;
#pragma unroll
        for (int s = 0; s < 4; ++s) {
            int slot = s * 4 + n;
            float wgt = __builtin_amdgcn_exp2f((ms[s] - m) * L2E) * ls[s];
            num += wgt * (float)((const f16*)g_opart)[slot * CHW + off];
            den += wgt;
        }
        float o = (den > 1e-30f) ? num / den : 0.f;
        if (mode == 0) {
            float xvv = bf2f(((const ushort_t*)xv)[n * CHW + off]);
            ((ushort_t*)outv)[n * CHW + off] = f2bf(fin0(xvv + gam * o));
        } else {
            float xvv = ((const float*)xv)[n * CHW + off];
            ((float*)outv)[n * CHW + off] = fin0(xvv + gam * o);
        }
    }
}

extern "C" void kernel_launch(void* const* d_in, const int* in_sizes, int n_in,
                              void* d_out, int out_size, void* d_ws, size_t ws_size,
                              hipStream_t stream) {
    (void)d_ws; (void)ws_size;
    bool ok = (n_in == 8) &&
              in_sizes[0] == 4 * CHW &&
              in_sizes[1] == C_DIM * C_DIM && in_sizes[2] == C_DIM &&
              in_sizes[3] == C_DIM * C_DIM && in_sizes[4] == C_DIM &&
              in_sizes[5] == C_DIM * C_DIM && in_sizes[6] == C_DIM &&
              in_sizes[7] == 1 && out_size == 4 * CHW;
    if (!ok) {
        hipLaunchKernelGGL(k_sentinel, dim3((out_size + 255) / 256), dim3(256), 0, stream,
                           (ushort_t*)d_out, out_size);
        return;
    }
    hipLaunchKernelGGL(k_probe, dim3(1), dim3(64), 0, stream, d_in[0]);
    hipLaunchKernelGGL(k_transpose, dim3(64, 4, 4), dim3(256), 0, stream, d_in[0]);
    hipLaunchKernelGGL(k_proj, dim3(32, 6, 4), dim3(256), 0, stream,
                       d_in[1], d_in[2], d_in[3], d_in[4], d_in[5], d_in[6]);
    hipLaunchKernelGGL(k_attn, dim3(512), dim3(256), 0, stream);
    hipLaunchKernelGGL(k_combine, dim3(CHW / 1024, 4), dim3(256), 0, stream,
                       d_in[0], d_in[7], d_out);
}

// Round 13
// 277.437 us; speedup vs baseline: 1.4421x; 1.4421x over previous
//
#include <hip/hip_runtime.h>

typedef unsigned short ushort_t;
typedef unsigned int u32;
typedef _Float16 f16;
typedef f16 f16x8 __attribute__((ext_vector_type(8)));
typedef f16 f16x2 __attribute__((ext_vector_type(2)));
typedef ushort_t u16x8 __attribute__((ext_vector_type(8)));
typedef float f32x4 __attribute__((ext_vector_type(4)));

#define C_DIM 256
#define HW 4096
#define CHW (C_DIM*HW)
#define L2E 1.4426950408889634f

// Device-global scratch. Internal pipeline f16.
__device__ __align__(16) f16 g_xbT[4 * CHW];
__device__ __align__(16) f16 g_q[4 * CHW];
__device__ __align__(16) f16 g_k[4 * CHW];
__device__ __align__(16) f16 g_v[4 * CHW];
__device__ __align__(16) f16 g_opart[16 * CHW];   // [slot=jq*4+n][c][i] normalized O^T
__device__ float g_ml[16 * 2 * HW];               // [slot][{m,l}][i]

__device__ __forceinline__ float bf2f(ushort_t h) {
    union { u32 u; float f; } v; v.u = ((u32)h) << 16; return v.f;
}
__device__ __forceinline__ ushort_t f2bf(float f) {
    union { float f; u32 u; } v; v.f = f;
    u32 r = v.u + 0x7FFF + ((v.u >> 16) & 1);
    return (ushort_t)(r >> 16);
}
__device__ __forceinline__ float fin0(float v) {
    return (v > -1e30f && v < 1e30f) ? v : 0.f;
}
__device__ __forceinline__ f16 sf16(float v) {
    return (f16)((v > -1e4f && v < 1e4f) ? v : 0.f);
}
__device__ __forceinline__ void gl2lds16(const f16* g, f16* l) {
    __builtin_amdgcn_global_load_lds(
        (const __attribute__((address_space(1))) u32*)g,
        (__attribute__((address_space(3))) u32*)l, 16, 0, 0);
}
// Local dtype probe: read 64 halves as bf16; f32-misread low-halves decode huge.
// Wave-uniform result (all lanes agree after butterfly). ~20 cyc, no extra launch.
__device__ __forceinline__ int probe_mode(const void* p) {
    int lane = threadIdx.x & 63;
    float v = fabsf(bf2f(((const ushort_t*)p)[lane]));
    v = (v < 1e6f) ? v : 1e6f;
#pragma unroll
    for (int d = 1; d < 64; d <<= 1) v += __shfl_xor(v, d, 64);
    return (v * (1.f / 64.f) > 100.f) ? 1 : 0;
}

__global__ void k_sentinel(ushort_t* out, int n) {
    int i = blockIdx.x * 256 + threadIdx.x;
    if (i < n) out[i] = f2bf(777.f);
}

// ---------------- kernel 1: x (N,C,HW) -> g_xbT f16 (N,HW,C) ----------------
__global__ __launch_bounds__(256) void k_transpose(const void* __restrict__ xv) {
    __shared__ f16 t[64][66];
    int mode = probe_mode(xv);
    int n = blockIdx.z, c0 = blockIdx.y * 64, l0 = blockIdx.x * 64;
    int tid = threadIdx.x;
    f16* ob = g_xbT + n * CHW;
    int lq = (tid & 15) * 4;
    int cl = tid >> 4;
    if (mode == 0) {
        const ushort_t* xb = (const ushort_t*)xv + n * CHW;
#pragma unroll
        for (int p = 0; p < 4; ++p) {
            int c = cl + 16 * p;
            ushort4 v = *(const ushort4*)(xb + (c0 + c) * HW + l0 + lq);
            t[lq + 0][c] = sf16(bf2f(v.x));
            t[lq + 1][c] = sf16(bf2f(v.y));
            t[lq + 2][c] = sf16(bf2f(v.z));
            t[lq + 3][c] = sf16(bf2f(v.w));
        }
    } else {
        const float* xb = (const float*)xv + n * CHW;
#pragma unroll
        for (int p = 0; p < 4; ++p) {
            int c = cl + 16 * p;
            float4 v = *(const float4*)(xb + (c0 + c) * HW + l0 + lq);
            t[lq + 0][c] = sf16(v.x);
            t[lq + 1][c] = sf16(v.y);
            t[lq + 2][c] = sf16(v.z);
            t[lq + 3][c] = sf16(v.w);
        }
    }
    __syncthreads();
    int c2 = (tid & 31) * 2;
    int lr = tid >> 5;
#pragma unroll
    for (int p = 0; p < 8; ++p) {
        int l = lr + 8 * p;
        u32 pair = *(const u32*)&t[l][c2];
        *(u32*)(ob + (l0 + l) * C_DIM + c0 + c2) = pair;
    }
}

// ---------------- kernel 2: projections (f16 MFMA) ----------------
__global__ __launch_bounds__(256) void k_proj(
    const void* __restrict__ Wq, const void* __restrict__ bq,
    const void* __restrict__ Wk, const void* __restrict__ bk,
    const void* __restrict__ Wv, const void* __restrict__ bv)
{
    __shared__ __align__(16) f16 lds_x[128 * 64];
    __shared__ __align__(16) f16 lds_w[128 * 64];
    int l0 = blockIdx.x * 128;
    int og0 = blockIdx.y * 128;
    int n = blockIdx.z;
    int mat = og0 >> 8;       // 0=q,1=k,2=v
    int om0 = og0 & 255;
    const void* W = (mat == 0) ? Wq : (mat == 1) ? Wk : Wv;
    const void* bias = (mat == 0) ? bq : (mat == 1) ? bk : bv;
    int mode = probe_mode(W);
    int tid = threadIdx.x, w = tid >> 6, lane = tid & 63;
    int quad = lane >> 4, l16 = lane & 15;
    const f16* xb = g_xbT + n * CHW;

    f32x4 acc[2][8];
#pragma unroll
    for (int a = 0; a < 2; a++)
#pragma unroll
        for (int b = 0; b < 8; b++) acc[a][b] = f32x4{0.f, 0.f, 0.f, 0.f};

    for (int ch = 0; ch < 4; ++ch) {
        int cc0 = ch * 64;
        f16x8 xs[4], wsr[4];
#pragma unroll
        for (int ti = 0; ti < 4; ++ti) {
            int s = (w * 4 + ti) * 64 + lane;
            int row = s >> 3, gp = s & 7;
            xs[ti] = *(const f16x8*)(xb + (l0 + row) * C_DIM + cc0 + gp * 8);
            f16x8 h;
            if (mode == 0) {
                u16x8 wv = *(const u16x8*)((const ushort_t*)W + (om0 + row) * C_DIM + cc0 + gp * 8);
#pragma unroll
                for (int e = 0; e < 8; e++) h[e] = sf16(bf2f(wv[e]));
            } else {
                const float* wf = (const float*)W + (om0 + row) * C_DIM + cc0 + gp * 8;
#pragma unroll
                for (int e = 0; e < 8; e++) h[e] = sf16(wf[e]);
            }
            wsr[ti] = h;
        }
        __syncthreads();
#pragma unroll
        for (int ti = 0; ti < 4; ++ti) {
            int s = (w * 4 + ti) * 64 + lane;
            int row = s >> 3, gp = s & 7;
            int pos = gp ^ (row & 7);
            *(f16x8*)(lds_x + (row * 8 + pos) * 8) = xs[ti];
            *(f16x8*)(lds_w + (row * 8 + pos) * 8) = wsr[ti];
        }
        __syncthreads();
#pragma unroll
        for (int ks = 0; ks < 2; ++ks) {
            f16x8 af[2];
#pragma unroll
            for (int mt = 0; mt < 2; ++mt) {
                int row = w * 32 + mt * 16 + l16;
                int g = ks * 4 + quad;
                int pos = g ^ (row & 7);
                af[mt] = *(const f16x8*)(lds_x + (row * 8 + pos) * 8);
            }
#pragma unroll
            for (int nt = 0; nt < 8; ++nt) {
                int rowo = nt * 16 + l16;
                int g = ks * 4 + quad;
                int pos = g ^ (rowo & 7);
                f16x8 bfv = *(const f16x8*)(lds_w + (rowo * 8 + pos) * 8);
                if (mat < 2) {
                    acc[0][nt] = __builtin_amdgcn_mfma_f32_16x16x32_f16(af[0], bfv, acc[0][nt], 0, 0, 0);
                    acc[1][nt] = __builtin_amdgcn_mfma_f32_16x16x32_f16(af[1], bfv, acc[1][nt], 0, 0, 0);
                } else {
                    acc[0][nt] = __builtin_amdgcn_mfma_f32_16x16x32_f16(bfv, af[0], acc[0][nt], 0, 0, 0);
                    acc[1][nt] = __builtin_amdgcn_mfma_f32_16x16x32_f16(bfv, af[1], acc[1][nt], 0, 0, 0);
                }
            }
        }
        __syncthreads();
    }

    auto loadb = [&](int i) -> float {
        return mode ? ((const float*)bias)[i] : bf2f(((const ushort_t*)bias)[i]);
    };
    if (mat < 2) {
        f16* T = ((mat == 0) ? g_q : g_k) + n * CHW;
        float bvv[8];
#pragma unroll
        for (int nt = 0; nt < 8; nt++) bvv[nt] = loadb(om0 + nt * 16 + l16);
#pragma unroll
        for (int mt = 0; mt < 2; mt++)
#pragma unroll
            for (int nt = 0; nt < 8; nt++)
#pragma unroll
                for (int r = 0; r < 4; r++) {
                    int l = l0 + w * 32 + mt * 16 + quad * 4 + r;
                    int o = om0 + nt * 16 + l16;
                    T[l * C_DIM + o] = sf16(acc[mt][nt][r] + bvv[nt]);
                }
    } else {
        f16* T = g_v + n * CHW;
#pragma unroll
        for (int mt = 0; mt < 2; mt++)
#pragma unroll
            for (int nt = 0; nt < 8; nt++)
#pragma unroll
                for (int r = 0; r < 4; r++) {
                    int o = om0 + nt * 16 + quad * 4 + r;
                    int l = l0 + w * 32 + mt * 16 + l16;
                    T[o * HW + l] = sf16(acc[mt][nt][r] + loadb(o));
                }
    }
}

// ---------------- kernel 3: flash attention (R10 structure, verified 143.7 us) ----------------
// 512 blocks x 256 thr, 58 KB LDS -> 2 blocks/CU. Offset-based LDS addressing
// (32 ints) — NOT absolute pointers (96 VGPRs -> scratch spill, R12's 15x fetch).
__global__ __launch_bounds__(256, 2) void k_attn() {
    __shared__ __align__(16) char smem[59392];
    f16* kbuf = (f16*)smem;             // 2 x 8192 f16 (32 j x 32 granules, swizzled)
    f16* vbuf = (f16*)(smem + 32768);   // 8192 f16 (256 c x 4 granules, swizzled)
    f16* pb   = (f16*)(smem + 49152);   // 4 waves x 2 mt x 16 i x 40 f16

    int bid = blockIdx.x;
    int x8 = bid & 7;
    int n = x8 >> 1, jhi = x8 & 1;      // XCD sees fixed (n, j-half)
    int rest = bid >> 3;
    int jlo = rest & 1;
    int i0 = (rest >> 1) * 128;         // 32 i-tiles of BM=128
    int jq = jhi * 2 + jlo;
    int tid = threadIdx.x, w = tid >> 6, lane = tid & 63;
    int quad = lane >> 4, l16 = lane & 15;

    const f16* Qb = g_q + n * CHW;
    const f16* Kb = g_k + n * CHW;
    const f16* Vb = g_v + n * CHW;
    f16* pw = pb + w * 1280;

    // Precomputed LDS read offsets (f16-element units)
    int koff0[8], koff1[8], voff[16];
#pragma unroll
    for (int kk = 0; kk < 8; kk++) {
        int g2 = kk * 4 + quad;
        int pos = (g2 & 24) | ((g2 & 7) ^ (l16 & 7));
        koff0[kk] = (l16 * 32 + pos) * 8;
        koff1[kk] = ((16 + l16) * 32 + pos) * 8;
    }
#pragma unroll
    for (int ct = 0; ct < 16; ct++) {
        int c = ct * 16 + l16;
        voff[ct] = (c * 4 + (quad ^ ((c >> 1) & 3))) * 8;
    }

    // Q fragments (B-operand), 2 i-groups of 16 per wave
    f16x8 qf[2][8];
#pragma unroll
    for (int mt = 0; mt < 2; mt++) {
        const f16* qrow = Qb + (i0 + w * 32 + mt * 16 + l16) * C_DIM + quad * 8;
#pragma unroll
        for (int kk = 0; kk < 8; kk++)
            qf[mt][kk] = *(const f16x8*)(qrow + kk * 32);
    }

    f32x4 o_acc[2][16];
#pragma unroll
    for (int mt = 0; mt < 2; mt++)
#pragma unroll
        for (int i = 0; i < 16; i++) o_acc[mt][i] = f32x4{0.f, 0.f, 0.f, 0.f};
    float m_[2] = {-1e30f, -1e30f}, l_[2] = {0.f, 0.f};

    auto stageK = [&](int jt, int buf) {
#pragma unroll
        for (int s = 0; s < 4; ++s) {
            int idx = s * 256 + tid;
            int j = idx >> 5, gp = idx & 31;
            int gg = (gp & 24) | ((gp & 7) ^ (j & 7));
            gl2lds16(Kb + (jt * 32 + j) * C_DIM + gg * 8,
                     kbuf + (buf * 1024 + s * 256 + w * 64) * 8);
        }
    };
    f16x8 vreg[4];
    int vgoff[4], vloff[4];
#pragma unroll
    for (int s = 0; s < 4; ++s) {
        int idx = s * 256 + tid;
        int c = idx >> 2, jp = idx & 3;
        int jg = jp ^ ((c >> 1) & 3);
        vgoff[s] = c * HW + jg * 8;
        vloff[s] = idx * 8;
    }
    auto loadV = [&](int jt) {
#pragma unroll
        for (int s = 0; s < 4; ++s)
            vreg[s] = *(const f16x8*)(Vb + vgoff[s] + jt * 32);
    };
    auto writeV = [&]() {
#pragma unroll
        for (int s = 0; s < 4; ++s)
            *(f16x8*)(vbuf + vloff[s]) = vreg[s];
    };

    int jt0 = jq * 32;
    stageK(jt0, 0);
    loadV(jt0);
    writeV();
    __syncthreads();   // K(0) drained, V(0) visible

    for (int it = 0; it < 32; ++it) {
        int buf = it & 1;
        if (it + 1 < 32) {
            stageK(jt0 + it + 1, buf ^ 1);  // async into other K buffer
            loadV(jt0 + it + 1);            // V prefetch into registers
        }

        const f16* kb = kbuf + buf * 8192;

        // ---- S^T(it) = K Q^T ----
        f32x4 st[2][2];
        st[0][0] = f32x4{0.f,0.f,0.f,0.f}; st[0][1] = f32x4{0.f,0.f,0.f,0.f};
        st[1][0] = f32x4{0.f,0.f,0.f,0.f}; st[1][1] = f32x4{0.f,0.f,0.f,0.f};
#pragma unroll
        for (int kk = 0; kk < 8; kk++) {
            f16x8 kf0 = *(const f16x8*)(kb + koff0[kk]);
            f16x8 kf1 = *(const f16x8*)(kb + koff1[kk]);
            st[0][0] = __builtin_amdgcn_mfma_f32_16x16x32_f16(kf0, qf[0][kk], st[0][0], 0, 0, 0);
            st[0][1] = __builtin_amdgcn_mfma_f32_16x16x32_f16(kf1, qf[0][kk], st[0][1], 0, 0, 0);
            st[1][0] = __builtin_amdgcn_mfma_f32_16x16x32_f16(kf0, qf[1][kk], st[1][0], 0, 0, 0);
            st[1][1] = __builtin_amdgcn_mfma_f32_16x16x32_f16(kf1, qf[1][kk], st[1][1], 0, 0, 0);
        }

        // ---- per-lane online softmax (quantized max) ----
        float al[2];
        float pv0[2][4], pv1[2][4];
#pragma unroll
        for (int mt = 0; mt < 2; mt++) {
            float smax = fmaxf(fmaxf(fmaxf(st[mt][0][0], st[mt][0][1]), fmaxf(st[mt][0][2], st[mt][0][3])),
                               fmaxf(fmaxf(st[mt][1][0], st[mt][1][1]), fmaxf(st[mt][1][2], st[mt][1][3])));
            smax = fmaxf(smax, __shfl_xor(smax, 16, 64));
            smax = fmaxf(smax, __shfl_xor(smax, 32, 64));
            float mq = __builtin_ceilf(smax * 0.125f) * 8.f;   // quantized up
            float mn = fmaxf(m_[mt], mq);
            al[mt] = __builtin_amdgcn_exp2f((m_[mt] - mn) * L2E);
            float rs = 0.f;
#pragma unroll
            for (int r = 0; r < 4; r++) {
                pv0[mt][r] = __builtin_amdgcn_exp2f((st[mt][0][r] - mn) * L2E);
                pv1[mt][r] = __builtin_amdgcn_exp2f((st[mt][1][r] - mn) * L2E);
                rs += pv0[mt][r] + pv1[mt][r];
            }
            m_[mt] = mn;
            rs += __shfl_xor(rs, 16, 64);
            rs += __shfl_xor(rs, 32, 64);
            l_[mt] = l_[mt] * al[mt] + rs;
        }
        if (__any((al[0] < 1.0f) || (al[1] < 1.0f))) {
#pragma unroll
            for (int mt = 0; mt < 2; mt++)
#pragma unroll
                for (int t = 0; t < 16; t++) o_acc[mt][t] *= al[mt];
        }

        // ---- P^T to LDS [i][j], read back as B-frag ----
#pragma unroll
        for (int mt = 0; mt < 2; mt++) {
            f16* pm = pw + mt * 640 + l16 * 40;
            *(f16x2*)(pm + quad * 4)          = f16x2{(f16)pv0[mt][0], (f16)pv0[mt][1]};
            *(f16x2*)(pm + quad * 4 + 2)      = f16x2{(f16)pv0[mt][2], (f16)pv0[mt][3]};
            *(f16x2*)(pm + 16 + quad * 4)     = f16x2{(f16)pv1[mt][0], (f16)pv1[mt][1]};
            *(f16x2*)(pm + 16 + quad * 4 + 2) = f16x2{(f16)pv1[mt][2], (f16)pv1[mt][3]};
        }
        asm volatile("" ::: "memory");
        f16x8 pf0 = *(const f16x8*)(pw + l16 * 40 + quad * 8);
        f16x8 pf1 = *(const f16x8*)(pw + 640 + l16 * 40 + quad * 8);

        // ---- O^T += V P^T ----
#pragma unroll
        for (int ct = 0; ct < 16; ++ct) {
            f16x8 vf = *(const f16x8*)(vbuf + voff[ct]);
            o_acc[0][ct] = __builtin_amdgcn_mfma_f32_16x16x32_f16(vf, pf0, o_acc[0][ct], 0, 0, 0);
            o_acc[1][ct] = __builtin_amdgcn_mfma_f32_16x16x32_f16(vf, pf1, o_acc[1][ct], 0, 0, 0);
        }

        __syncthreads();   // all vbuf/kb reads done; K(it+1)/V(it+1) loads landed
        if (it + 1 < 32) {
            writeV();      // vbuf <- V(it+1)
            __syncthreads();
        }
    }

    // ---- write partials: normalized O^T (f16) + m,l (f32) ----
    int slot = jq * 4 + n;
    if (quad == 0) {
#pragma unroll
        for (int mt = 0; mt < 2; mt++) {
            int i = i0 + w * 32 + mt * 16 + l16;
            g_ml[(slot * 2 + 0) * HW + i] = m_[mt];
            g_ml[(slot * 2 + 1) * HW + i] = l_[mt];
        }
    }
    f16* ob = g_opart + slot * CHW;
#pragma unroll
    for (int mt = 0; mt < 2; mt++) {
        int ig = i0 + w * 32 + mt * 16 + l16;
        float inv = (l_[mt] > 1e-30f) ? 1.0f / l_[mt] : 0.f;
#pragma unroll
        for (int ct = 0; ct < 16; ct++)
#pragma unroll
            for (int r = 0; r < 4; r++) {
                int c = ct * 16 + quad * 4 + r;
                ob[c * HW + ig] = (f16)(o_acc[mt][ct][r] * inv);
            }
    }
}

// ---------------- kernel 4: merge 4 j-quarters + residual + store ----------------
__global__ __launch_bounds__(256) void k_combine(
    const void* __restrict__ xv, const void* __restrict__ gv, void* __restrict__ outv)
{
    int mode = probe_mode(xv);
    float gam = fin0(mode ? ((const float*)gv)[0] : bf2f(((const ushort_t*)gv)[0]));
    int n = blockIdx.y;
    int base = blockIdx.x * 1024;
#pragma unroll
    for (int e = 0; e < 4; ++e) {
        int off = base + e * 256 + threadIdx.x;
        int i = off & (HW - 1);
        float m = -1e30f;
        float ms[4], ls[4];
#pragma unroll
        for (int s = 0; s < 4; ++s) {
            int slot = s * 4 + n;
            ms[s] = g_ml[(slot * 2 + 0) * HW + i];
            ls[s] = g_ml[(slot * 2 + 1) * HW + i];
            m = fmaxf(m, ms[s]);
        }
        float num = 0.f, den = 0.f;
#pragma unroll
        for (int s = 0; s < 4; ++s) {
            int slot = s * 4 + n;
            float wgt = __builtin_amdgcn_exp2f((ms[s] - m) * L2E) * ls[s];
            num += wgt * (float)((const f16*)g_opart)[slot * CHW + off];
            den += wgt;
        }
        float o = (den > 1e-30f) ? num / den : 0.f;
        if (mode == 0) {
            float xvv = bf2f(((const ushort_t*)xv)[n * CHW + off]);
            ((ushort_t*)outv)[n * CHW + off] = f2bf(fin0(xvv + gam * o));
        } else {
            float xvv = ((const float*)xv)[n * CHW + off];
            ((float*)outv)[n * CHW + off] = fin0(xvv + gam * o);
        }
    }
}

extern "C" void kernel_launch(void* const* d_in, const int* in_sizes, int n_in,
                              void* d_out, int out_size, void* d_ws, size_t ws_size,
                              hipStream_t stream) {
    (void)d_ws; (void)ws_size;
    bool ok = (n_in == 8) &&
              in_sizes[0] == 4 * CHW &&
              in_sizes[1] == C_DIM * C_DIM && in_sizes[2] == C_DIM &&
              in_sizes[3] == C_DIM * C_DIM && in_sizes[4] == C_DIM &&
              in_sizes[5] == C_DIM * C_DIM && in_sizes[6] == C_DIM &&
              in_sizes[7] == 1 && out_size == 4 * CHW;
    if (!ok) {
        hipLaunchKernelGGL(k_sentinel, dim3((out_size + 255) / 256), dim3(256), 0, stream,
                           (ushort_t*)d_out, out_size);
        return;
    }
    hipLaunchKernelGGL(k_transpose, dim3(64, 4, 4), dim3(256), 0, stream, d_in[0]);
    hipLaunchKernelGGL(k_proj, dim3(32, 6, 4), dim3(256), 0, stream,
                       d_in[1], d_in[2], d_in[3], d_in[4], d_in[5], d_in[6]);
    hipLaunchKernelGGL(k_attn, dim3(512), dim3(256), 0, stream);
    hipLaunchKernelGGL(k_combine, dim3(CHW / 1024, 4), dim3(256), 0, stream,
                       d_in[0], d_in[7], d_out);
}

// Round 14
// 276.010 us; speedup vs baseline: 1.4496x; 1.0052x over previous
//
#include <hip/hip_runtime.h>

typedef unsigned short ushort_t;
typedef unsigned int u32;
typedef _Float16 f16;
typedef f16 f16x8 __attribute__((ext_vector_type(8)));
typedef f16 f16x2 __attribute__((ext_vector_type(2)));
typedef ushort_t u16x8 __attribute__((ext_vector_type(8)));
typedef float f32x4 __attribute__((ext_vector_type(4)));

#define C_DIM 256
#define HW 4096
#define CHW (C_DIM*HW)
#define L2E 1.4426950408889634f

// Device-global scratch. Internal pipeline f16.
__device__ __align__(16) f16 g_xbT[4 * CHW];
__device__ __align__(16) f16 g_q[4 * CHW];
__device__ __align__(16) f16 g_k[4 * CHW];
__device__ __align__(16) f16 g_v[4 * CHW];
__device__ __align__(16) f16 g_opart[16 * CHW];   // [slot=jq*4+n][c][i] normalized O^T
__device__ __align__(16) float g_ml[16 * 2 * HW]; // [slot][{m,l}][i]

__device__ __forceinline__ float bf2f(ushort_t h) {
    union { u32 u; float f; } v; v.u = ((u32)h) << 16; return v.f;
}
__device__ __forceinline__ ushort_t f2bf(float f) {
    union { float f; u32 u; } v; v.f = f;
    u32 r = v.u + 0x7FFF + ((v.u >> 16) & 1);
    return (ushort_t)(r >> 16);
}
__device__ __forceinline__ float fin0(float v) {
    return (v > -1e30f && v < 1e30f) ? v : 0.f;
}
__device__ __forceinline__ f16 sf16(float v) {
    return (f16)((v > -1e4f && v < 1e4f) ? v : 0.f);
}
__device__ __forceinline__ void gl2lds16(const f16* g, f16* l) {
    __builtin_amdgcn_global_load_lds(
        (const __attribute__((address_space(1))) u32*)g,
        (__attribute__((address_space(3))) u32*)l, 16, 0, 0);
}
// Local dtype probe: read 64 halves as bf16; f32-misread low-halves decode huge.
__device__ __forceinline__ int probe_mode(const void* p) {
    int lane = threadIdx.x & 63;
    float v = fabsf(bf2f(((const ushort_t*)p)[lane]));
    v = (v < 1e6f) ? v : 1e6f;
#pragma unroll
    for (int d = 1; d < 64; d <<= 1) v += __shfl_xor(v, d, 64);
    return (v * (1.f / 64.f) > 100.f) ? 1 : 0;
}

__global__ void k_sentinel(ushort_t* out, int n) {
    int i = blockIdx.x * 256 + threadIdx.x;
    if (i < n) out[i] = f2bf(777.f);
}

// ---------------- kernel 1: x (N,C,HW) -> g_xbT f16 (N,HW,C) ----------------
__global__ __launch_bounds__(256) void k_transpose(const void* __restrict__ xv) {
    __shared__ f16 t[64][66];
    int mode = probe_mode(xv);
    int n = blockIdx.z, c0 = blockIdx.y * 64, l0 = blockIdx.x * 64;
    int tid = threadIdx.x;
    f16* ob = g_xbT + n * CHW;
    int lq = (tid & 15) * 4;
    int cl = tid >> 4;
    if (mode == 0) {
        const ushort_t* xb = (const ushort_t*)xv + n * CHW;
#pragma unroll
        for (int p = 0; p < 4; ++p) {
            int c = cl + 16 * p;
            ushort4 v = *(const ushort4*)(xb + (c0 + c) * HW + l0 + lq);
            t[lq + 0][c] = sf16(bf2f(v.x));
            t[lq + 1][c] = sf16(bf2f(v.y));
            t[lq + 2][c] = sf16(bf2f(v.z));
            t[lq + 3][c] = sf16(bf2f(v.w));
        }
    } else {
        const float* xb = (const float*)xv + n * CHW;
#pragma unroll
        for (int p = 0; p < 4; ++p) {
            int c = cl + 16 * p;
            float4 v = *(const float4*)(xb + (c0 + c) * HW + l0 + lq);
            t[lq + 0][c] = sf16(v.x);
            t[lq + 1][c] = sf16(v.y);
            t[lq + 2][c] = sf16(v.z);
            t[lq + 3][c] = sf16(v.w);
        }
    }
    __syncthreads();
    int c2 = (tid & 31) * 2;
    int lr = tid >> 5;
#pragma unroll
    for (int p = 0; p < 8; ++p) {
        int l = lr + 8 * p;
        u32 pair = *(const u32*)&t[l][c2];
        *(u32*)(ob + (l0 + l) * C_DIM + c0 + c2) = pair;
    }
}

// ---------------- kernel 2: projections (f16 MFMA) ----------------
__global__ __launch_bounds__(256) void k_proj(
    const void* __restrict__ Wq, const void* __restrict__ bq,
    const void* __restrict__ Wk, const void* __restrict__ bk,
    const void* __restrict__ Wv, const void* __restrict__ bv)
{
    __shared__ __align__(16) f16 lds_x[128 * 64];
    __shared__ __align__(16) f16 lds_w[128 * 64];
    int l0 = blockIdx.x * 128;
    int og0 = blockIdx.y * 128;
    int n = blockIdx.z;
    int mat = og0 >> 8;       // 0=q,1=k,2=v
    int om0 = og0 & 255;
    const void* W = (mat == 0) ? Wq : (mat == 1) ? Wk : Wv;
    const void* bias = (mat == 0) ? bq : (mat == 1) ? bk : bv;
    int mode = probe_mode(W);
    int tid = threadIdx.x, w = tid >> 6, lane = tid & 63;
    int quad = lane >> 4, l16 = lane & 15;
    const f16* xb = g_xbT + n * CHW;

    f32x4 acc[2][8];
#pragma unroll
    for (int a = 0; a < 2; a++)
#pragma unroll
        for (int b = 0; b < 8; b++) acc[a][b] = f32x4{0.f, 0.f, 0.f, 0.f};

    for (int ch = 0; ch < 4; ++ch) {
        int cc0 = ch * 64;
        f16x8 xs[4], wsr[4];
#pragma unroll
        for (int ti = 0; ti < 4; ++ti) {
            int s = (w * 4 + ti) * 64 + lane;
            int row = s >> 3, gp = s & 7;
            xs[ti] = *(const f16x8*)(xb + (l0 + row) * C_DIM + cc0 + gp * 8);
            f16x8 h;
            if (mode == 0) {
                u16x8 wv = *(const u16x8*)((const ushort_t*)W + (om0 + row) * C_DIM + cc0 + gp * 8);
#pragma unroll
                for (int e = 0; e < 8; e++) h[e] = sf16(bf2f(wv[e]));
            } else {
                const float* wf = (const float*)W + (om0 + row) * C_DIM + cc0 + gp * 8;
#pragma unroll
                for (int e = 0; e < 8; e++) h[e] = sf16(wf[e]);
            }
            wsr[ti] = h;
        }
        __syncthreads();
#pragma unroll
        for (int ti = 0; ti < 4; ++ti) {
            int s = (w * 4 + ti) * 64 + lane;
            int row = s >> 3, gp = s & 7;
            int pos = gp ^ (row & 7);
            *(f16x8*)(lds_x + (row * 8 + pos) * 8) = xs[ti];
            *(f16x8*)(lds_w + (row * 8 + pos) * 8) = wsr[ti];
        }
        __syncthreads();
#pragma unroll
        for (int ks = 0; ks < 2; ++ks) {
            f16x8 af[2];
#pragma unroll
            for (int mt = 0; mt < 2; ++mt) {
                int row = w * 32 + mt * 16 + l16;
                int g = ks * 4 + quad;
                int pos = g ^ (row & 7);
                af[mt] = *(const f16x8*)(lds_x + (row * 8 + pos) * 8);
            }
#pragma unroll
            for (int nt = 0; nt < 8; ++nt) {
                int rowo = nt * 16 + l16;
                int g = ks * 4 + quad;
                int pos = g ^ (rowo & 7);
                f16x8 bfv = *(const f16x8*)(lds_w + (rowo * 8 + pos) * 8);
                if (mat < 2) {
                    acc[0][nt] = __builtin_amdgcn_mfma_f32_16x16x32_f16(af[0], bfv, acc[0][nt], 0, 0, 0);
                    acc[1][nt] = __builtin_amdgcn_mfma_f32_16x16x32_f16(af[1], bfv, acc[1][nt], 0, 0, 0);
                } else {
                    acc[0][nt] = __builtin_amdgcn_mfma_f32_16x16x32_f16(bfv, af[0], acc[0][nt], 0, 0, 0);
                    acc[1][nt] = __builtin_amdgcn_mfma_f32_16x16x32_f16(bfv, af[1], acc[1][nt], 0, 0, 0);
                }
            }
        }
        __syncthreads();
    }

    auto loadb = [&](int i) -> float {
        return mode ? ((const float*)bias)[i] : bf2f(((const ushort_t*)bias)[i]);
    };
    if (mat < 2) {
        f16* T = ((mat == 0) ? g_q : g_k) + n * CHW;
        float bvv[8];
#pragma unroll
        for (int nt = 0; nt < 8; nt++) bvv[nt] = loadb(om0 + nt * 16 + l16);
#pragma unroll
        for (int mt = 0; mt < 2; mt++)
#pragma unroll
            for (int nt = 0; nt < 8; nt++)
#pragma unroll
                for (int r = 0; r < 4; r++) {
                    int l = l0 + w * 32 + mt * 16 + quad * 4 + r;
                    int o = om0 + nt * 16 + l16;
                    T[l * C_DIM + o] = sf16(acc[mt][nt][r] + bvv[nt]);
                }
    } else {
        f16* T = g_v + n * CHW;
#pragma unroll
        for (int mt = 0; mt < 2; mt++)
#pragma unroll
            for (int nt = 0; nt < 8; nt++)
#pragma unroll
                for (int r = 0; r < 4; r++) {
                    int o = om0 + nt * 16 + quad * 4 + r;
                    int l = l0 + w * 32 + mt * 16 + l16;
                    T[o * HW + l] = sf16(acc[mt][nt][r] + loadb(o));
                }
    }
}

// ---------------- kernel 3: flash attention (R10 structure, verified 143 us) ----------------
__global__ __launch_bounds__(256, 2) void k_attn() {
    __shared__ __align__(16) char smem[59392];
    f16* kbuf = (f16*)smem;             // 2 x 8192 f16 (32 j x 32 granules, swizzled)
    f16* vbuf = (f16*)(smem + 32768);   // 8192 f16 (256 c x 4 granules, swizzled)
    f16* pb   = (f16*)(smem + 49152);   // 4 waves x 2 mt x 16 i x 40 f16

    int bid = blockIdx.x;
    int x8 = bid & 7;
    int n = x8 >> 1, jhi = x8 & 1;
    int rest = bid >> 3;
    int jlo = rest & 1;
    int i0 = (rest >> 1) * 128;
    int jq = jhi * 2 + jlo;
    int tid = threadIdx.x, w = tid >> 6, lane = tid & 63;
    int quad = lane >> 4, l16 = lane & 15;

    const f16* Qb = g_q + n * CHW;
    const f16* Kb = g_k + n * CHW;
    const f16* Vb = g_v + n * CHW;
    f16* pw = pb + w * 1280;

    int koff0[8], koff1[8], voff[16];
#pragma unroll
    for (int kk = 0; kk < 8; kk++) {
        int g2 = kk * 4 + quad;
        int pos = (g2 & 24) | ((g2 & 7) ^ (l16 & 7));
        koff0[kk] = (l16 * 32 + pos) * 8;
        koff1[kk] = ((16 + l16) * 32 + pos) * 8;
    }
#pragma unroll
    for (int ct = 0; ct < 16; ct++) {
        int c = ct * 16 + l16;
        voff[ct] = (c * 4 + (quad ^ ((c >> 1) & 3))) * 8;
    }

    f16x8 qf[2][8];
#pragma unroll
    for (int mt = 0; mt < 2; mt++) {
        const f16* qrow = Qb + (i0 + w * 32 + mt * 16 + l16) * C_DIM + quad * 8;
#pragma unroll
        for (int kk = 0; kk < 8; kk++)
            qf[mt][kk] = *(const f16x8*)(qrow + kk * 32);
    }

    f32x4 o_acc[2][16];
#pragma unroll
    for (int mt = 0; mt < 2; mt++)
#pragma unroll
        for (int i = 0; i < 16; i++) o_acc[mt][i] = f32x4{0.f, 0.f, 0.f, 0.f};
    float m_[2] = {-1e30f, -1e30f}, l_[2] = {0.f, 0.f};

    auto stageK = [&](int jt, int buf) {
#pragma unroll
        for (int s = 0; s < 4; ++s) {
            int idx = s * 256 + tid;
            int j = idx >> 5, gp = idx & 31;
            int gg = (gp & 24) | ((gp & 7) ^ (j & 7));
            gl2lds16(Kb + (jt * 32 + j) * C_DIM + gg * 8,
                     kbuf + (buf * 1024 + s * 256 + w * 64) * 8);
        }
    };
    f16x8 vreg[4];
    int vgoff[4], vloff[4];
#pragma unroll
    for (int s = 0; s < 4; ++s) {
        int idx = s * 256 + tid;
        int c = idx >> 2, jp = idx & 3;
        int jg = jp ^ ((c >> 1) & 3);
        vgoff[s] = c * HW + jg * 8;
        vloff[s] = idx * 8;
    }
    auto loadV = [&](int jt) {
#pragma unroll
        for (int s = 0; s < 4; ++s)
            vreg[s] = *(const f16x8*)(Vb + vgoff[s] + jt * 32);
    };
    auto writeV = [&]() {
#pragma unroll
        for (int s = 0; s < 4; ++s)
            *(f16x8*)(vbuf + vloff[s]) = vreg[s];
    };

    int jt0 = jq * 32;
    stageK(jt0, 0);
    loadV(jt0);
    writeV();
    __syncthreads();

    for (int it = 0; it < 32; ++it) {
        int buf = it & 1;
        if (it + 1 < 32) {
            stageK(jt0 + it + 1, buf ^ 1);
            loadV(jt0 + it + 1);
        }

        const f16* kb = kbuf + buf * 8192;

        f32x4 st[2][2];
        st[0][0] = f32x4{0.f,0.f,0.f,0.f}; st[0][1] = f32x4{0.f,0.f,0.f,0.f};
        st[1][0] = f32x4{0.f,0.f,0.f,0.f}; st[1][1] = f32x4{0.f,0.f,0.f,0.f};
#pragma unroll
        for (int kk = 0; kk < 8; kk++) {
            f16x8 kf0 = *(const f16x8*)(kb + koff0[kk]);
            f16x8 kf1 = *(const f16x8*)(kb + koff1[kk]);
            st[0][0] = __builtin_amdgcn_mfma_f32_16x16x32_f16(kf0, qf[0][kk], st[0][0], 0, 0, 0);
            st[0][1] = __builtin_amdgcn_mfma_f32_16x16x32_f16(kf1, qf[0][kk], st[0][1], 0, 0, 0);
            st[1][0] = __builtin_amdgcn_mfma_f32_16x16x32_f16(kf0, qf[1][kk], st[1][0], 0, 0, 0);
            st[1][1] = __builtin_amdgcn_mfma_f32_16x16x32_f16(kf1, qf[1][kk], st[1][1], 0, 0, 0);
        }

        float al[2];
        float pv0[2][4], pv1[2][4];
#pragma unroll
        for (int mt = 0; mt < 2; mt++) {
            float smax = fmaxf(fmaxf(fmaxf(st[mt][0][0], st[mt][0][1]), fmaxf(st[mt][0][2], st[mt][0][3])),
                               fmaxf(fmaxf(st[mt][1][0], st[mt][1][1]), fmaxf(st[mt][1][2], st[mt][1][3])));
            smax = fmaxf(smax, __shfl_xor(smax, 16, 64));
            smax = fmaxf(smax, __shfl_xor(smax, 32, 64));
            float mq = __builtin_ceilf(smax * 0.125f) * 8.f;
            float mn = fmaxf(m_[mt], mq);
            al[mt] = __builtin_amdgcn_exp2f((m_[mt] - mn) * L2E);
            float rs = 0.f;
#pragma unroll
            for (int r = 0; r < 4; r++) {
                pv0[mt][r] = __builtin_amdgcn_exp2f((st[mt][0][r] - mn) * L2E);
                pv1[mt][r] = __builtin_amdgcn_exp2f((st[mt][1][r] - mn) * L2E);
                rs += pv0[mt][r] + pv1[mt][r];
            }
            m_[mt] = mn;
            rs += __shfl_xor(rs, 16, 64);
            rs += __shfl_xor(rs, 32, 64);
            l_[mt] = l_[mt] * al[mt] + rs;
        }
        if (__any((al[0] < 1.0f) || (al[1] < 1.0f))) {
#pragma unroll
            for (int mt = 0; mt < 2; mt++)
#pragma unroll
                for (int t = 0; t < 16; t++) o_acc[mt][t] *= al[mt];
        }

#pragma unroll
        for (int mt = 0; mt < 2; mt++) {
            f16* pm = pw + mt * 640 + l16 * 40;
            *(f16x2*)(pm + quad * 4)          = f16x2{(f16)pv0[mt][0], (f16)pv0[mt][1]};
            *(f16x2*)(pm + quad * 4 + 2)      = f16x2{(f16)pv0[mt][2], (f16)pv0[mt][3]};
            *(f16x2*)(pm + 16 + quad * 4)     = f16x2{(f16)pv1[mt][0], (f16)pv1[mt][1]};
            *(f16x2*)(pm + 16 + quad * 4 + 2) = f16x2{(f16)pv1[mt][2], (f16)pv1[mt][3]};
        }
        asm volatile("" ::: "memory");
        f16x8 pf0 = *(const f16x8*)(pw + l16 * 40 + quad * 8);
        f16x8 pf1 = *(const f16x8*)(pw + 640 + l16 * 40 + quad * 8);

#pragma unroll
        for (int ct = 0; ct < 16; ++ct) {
            f16x8 vf = *(const f16x8*)(vbuf + voff[ct]);
            o_acc[0][ct] = __builtin_amdgcn_mfma_f32_16x16x32_f16(vf, pf0, o_acc[0][ct], 0, 0, 0);
            o_acc[1][ct] = __builtin_amdgcn_mfma_f32_16x16x32_f16(vf, pf1, o_acc[1][ct], 0, 0, 0);
        }

        __syncthreads();
        if (it + 1 < 32) {
            writeV();
            __syncthreads();
        }
    }

    // ---- write partials: mt-adjacent stores so each quad covers a full 64B line ----
    int slot = jq * 4 + n;
    if (quad == 0) {
#pragma unroll
        for (int mt = 0; mt < 2; mt++) {
            int i = i0 + w * 32 + mt * 16 + l16;
            g_ml[(slot * 2 + 0) * HW + i] = m_[mt];
            g_ml[(slot * 2 + 1) * HW + i] = l_[mt];
        }
    }
    f16* ob = g_opart + slot * CHW;
    int ig0 = i0 + w * 32 + l16;
    float inv0 = (l_[0] > 1e-30f) ? 1.0f / l_[0] : 0.f;
    float inv1 = (l_[1] > 1e-30f) ? 1.0f / l_[1] : 0.f;
#pragma unroll
    for (int ct = 0; ct < 16; ct++)
#pragma unroll
        for (int r = 0; r < 4; r++) {
            int c = ct * 16 + quad * 4 + r;
            ob[c * HW + ig0]      = (f16)(o_acc[0][ct][r] * inv0);
            ob[c * HW + ig0 + 16] = (f16)(o_acc[1][ct][r] * inv1);
        }
}

// ---------------- kernel 4: merge 4 j-quarters + residual + store (8-wide) ----------------
__global__ __launch_bounds__(256) void k_combine(
    const void* __restrict__ xv, const void* __restrict__ gv, void* __restrict__ outv)
{
    int mode = probe_mode(xv);
    float gam = fin0(mode ? ((const float*)gv)[0] : bf2f(((const ushort_t*)gv)[0]));
    int n = blockIdx.y;
    int off = blockIdx.x * 2048 + threadIdx.x * 8;   // 8 consecutive i, same c
    int i = off & (HW - 1);

    // per-slot loads (vectorized)
    u16x8 op[4];
    float ms[4][8], ls[4][8];
#pragma unroll
    for (int s = 0; s < 4; ++s) {
        int slot = s * 4 + n;
        op[s] = *(const u16x8*)((const ushort_t*)g_opart + slot * CHW + off);
        float4 mA = *(const float4*)&g_ml[(slot * 2 + 0) * HW + i];
        float4 mB = *(const float4*)&g_ml[(slot * 2 + 0) * HW + i + 4];
        float4 lA = *(const float4*)&g_ml[(slot * 2 + 1) * HW + i];
        float4 lB = *(const float4*)&g_ml[(slot * 2 + 1) * HW + i + 4];
        ms[s][0]=mA.x; ms[s][1]=mA.y; ms[s][2]=mA.z; ms[s][3]=mA.w;
        ms[s][4]=mB.x; ms[s][5]=mB.y; ms[s][6]=mB.z; ms[s][7]=mB.w;
        ls[s][0]=lA.x; ls[s][1]=lA.y; ls[s][2]=lA.z; ls[s][3]=lA.w;
        ls[s][4]=lB.x; ls[s][5]=lB.y; ls[s][6]=lB.z; ls[s][7]=lB.w;
    }

    float o[8];
#pragma unroll
    for (int e = 0; e < 8; ++e) {
        float m = fmaxf(fmaxf(ms[0][e], ms[1][e]), fmaxf(ms[2][e], ms[3][e]));
        float num = 0.f, den = 0.f;
#pragma unroll
        for (int s = 0; s < 4; ++s) {
            float wgt = __builtin_amdgcn_exp2f((ms[s][e] - m) * L2E) * ls[s][e];
            union { ushort_t u; f16 h; } cv; cv.u = (ushort_t)op[s][e];
            num += wgt * (float)cv.h;
            den += wgt;
        }
        o[e] = (den > 1e-30f) ? num / den : 0.f;
    }

    if (mode == 0) {
        u16x8 xp = *(const u16x8*)((const ushort_t*)xv + n * CHW + off);
        u16x8 res;
#pragma unroll
        for (int e = 0; e < 8; ++e)
            res[e] = f2bf(fin0(bf2f((ushort_t)xp[e]) + gam * o[e]));
        *(u16x8*)((ushort_t*)outv + n * CHW + off) = res;
    } else {
        const float* xb = (const float*)xv + n * CHW + off;
        float* outb = (float*)outv + n * CHW + off;
        float4 xA = *(const float4*)xb;
        float4 xB = *(const float4*)(xb + 4);
        float4 rA, rB;
        rA.x = fin0(xA.x + gam * o[0]); rA.y = fin0(xA.y + gam * o[1]);
        rA.z = fin0(xA.z + gam * o[2]); rA.w = fin0(xA.w + gam * o[3]);
        rB.x = fin0(xB.x + gam * o[4]); rB.y = fin0(xB.y + gam * o[5]);
        rB.z = fin0(xB.z + gam * o[6]); rB.w = fin0(xB.w + gam * o[7]);
        *(float4*)outb = rA;
        *(float4*)(outb + 4) = rB;
    }
}

extern "C" void kernel_launch(void* const* d_in, const int* in_sizes, int n_in,
                              void* d_out, int out_size, void* d_ws, size_t ws_size,
                              hipStream_t stream) {
    (void)d_ws; (void)ws_size;
    bool ok = (n_in == 8) &&
              in_sizes[0] == 4 * CHW &&
              in_sizes[1] == C_DIM * C_DIM && in_sizes[2] == C_DIM &&
              in_sizes[3] == C_DIM * C_DIM && in_sizes[4] == C_DIM &&
              in_sizes[5] == C_DIM * C_DIM && in_sizes[6] == C_DIM &&
              in_sizes[7] == 1 && out_size == 4 * CHW;
    if (!ok) {
        hipLaunchKernelGGL(k_sentinel, dim3((out_size + 255) / 256), dim3(256), 0, stream,
                           (ushort_t*)d_out, out_size);
        return;
    }
    hipLaunchKernelGGL(k_transpose, dim3(64, 4, 4), dim3(256), 0, stream, d_in[0]);
    hipLaunchKernelGGL(k_proj, dim3(32, 6, 4), dim3(256), 0, stream,
                       d_in[1], d_in[2], d_in[3], d_in[4], d_in[5], d_in[6]);
    hipLaunchKernelGGL(k_attn, dim3(512), dim3(256), 0, stream);
    hipLaunchKernelGGL(k_combine, dim3(CHW / 2048, 4), dim3(256), 0, stream,
                       d_in[0], d_in[7], d_out);
}

// Round 15
// 235.085 us; speedup vs baseline: 1.7019x; 1.1741x over previous
//
#include <hip/hip_runtime.h>

typedef unsigned short ushort_t;
typedef unsigned int u32;
typedef _Float16 f16;
typedef f16 f16x8 __attribute__((ext_vector_type(8)));
typedef f16 f16x2 __attribute__((ext_vector_type(2)));
typedef ushort_t u16x8 __attribute__((ext_vector_type(8)));
typedef float f32x4 __attribute__((ext_vector_type(4)));

#define C_DIM 256
#define HW 4096
#define CHW (C_DIM*HW)
#define L2E 1.4426950408889634f

// Device-global scratch. Internal pipeline f16.
__device__ __align__(16) f16 g_xbT[4 * CHW];
__device__ __align__(16) f16 g_q[4 * CHW];
__device__ __align__(16) f16 g_k[4 * CHW];
__device__ __align__(16) f16 g_v[4 * CHW];
__device__ __align__(16) f16 g_opart[16 * CHW];   // [slot=jq*4+n][c][i] normalized O^T
__device__ __align__(16) float g_ml[16 * 2 * HW]; // [slot][{m,l}][i]

__device__ __forceinline__ float bf2f(ushort_t h) {
    union { u32 u; float f; } v; v.u = ((u32)h) << 16; return v.f;
}
__device__ __forceinline__ ushort_t f2bf(float f) {
    union { float f; u32 u; } v; v.f = f;
    u32 r = v.u + 0x7FFF + ((v.u >> 16) & 1);
    return (ushort_t)(r >> 16);
}
__device__ __forceinline__ float fin0(float v) {
    return (v > -1e30f && v < 1e30f) ? v : 0.f;
}
__device__ __forceinline__ f16 sf16(float v) {
    return (f16)((v > -1e4f && v < 1e4f) ? v : 0.f);
}
__device__ __forceinline__ void gl2lds16(const f16* g, f16* l) {
    __builtin_amdgcn_global_load_lds(
        (const __attribute__((address_space(1))) u32*)g,
        (__attribute__((address_space(3))) u32*)l, 16, 0, 0);
}
// Local dtype probe: read 64 halves as bf16; f32-misread low-halves decode huge.
__device__ __forceinline__ int probe_mode(const void* p) {
    int lane = threadIdx.x & 63;
    float v = fabsf(bf2f(((const ushort_t*)p)[lane]));
    v = (v < 1e6f) ? v : 1e6f;
#pragma unroll
    for (int d = 1; d < 64; d <<= 1) v += __shfl_xor(v, d, 64);
    return (v * (1.f / 64.f) > 100.f) ? 1 : 0;
}

__global__ void k_sentinel(ushort_t* out, int n) {
    int i = blockIdx.x * 256 + threadIdx.x;
    if (i < n) out[i] = f2bf(777.f);
}

// ---------------- kernel 1: x (N,C,HW) -> g_xbT f16 (N,HW,C) ----------------
__global__ __launch_bounds__(256) void k_transpose(const void* __restrict__ xv) {
    __shared__ f16 t[64][66];
    int mode = probe_mode(xv);
    int n = blockIdx.z, c0 = blockIdx.y * 64, l0 = blockIdx.x * 64;
    int tid = threadIdx.x;
    f16* ob = g_xbT + n * CHW;
    int lq = (tid & 15) * 4;
    int cl = tid >> 4;
    if (mode == 0) {
        const ushort_t* xb = (const ushort_t*)xv + n * CHW;
#pragma unroll
        for (int p = 0; p < 4; ++p) {
            int c = cl + 16 * p;
            ushort4 v = *(const ushort4*)(xb + (c0 + c) * HW + l0 + lq);
            t[lq + 0][c] = sf16(bf2f(v.x));
            t[lq + 1][c] = sf16(bf2f(v.y));
            t[lq + 2][c] = sf16(bf2f(v.z));
            t[lq + 3][c] = sf16(bf2f(v.w));
        }
    } else {
        const float* xb = (const float*)xv + n * CHW;
#pragma unroll
        for (int p = 0; p < 4; ++p) {
            int c = cl + 16 * p;
            float4 v = *(const float4*)(xb + (c0 + c) * HW + l0 + lq);
            t[lq + 0][c] = sf16(v.x);
            t[lq + 1][c] = sf16(v.y);
            t[lq + 2][c] = sf16(v.z);
            t[lq + 3][c] = sf16(v.w);
        }
    }
    __syncthreads();
    int c2 = (tid & 31) * 2;
    int lr = tid >> 5;
#pragma unroll
    for (int p = 0; p < 8; ++p) {
        int l = lr + 8 * p;
        u32 pair = *(const u32*)&t[l][c2];
        *(u32*)(ob + (l0 + l) * C_DIM + c0 + c2) = pair;
    }
}

// ---------------- kernel 2: projections (f16 MFMA) ----------------
__global__ __launch_bounds__(256) void k_proj(
    const void* __restrict__ Wq, const void* __restrict__ bq,
    const void* __restrict__ Wk, const void* __restrict__ bk,
    const void* __restrict__ Wv, const void* __restrict__ bv)
{
    __shared__ __align__(16) f16 lds_x[128 * 64];
    __shared__ __align__(16) f16 lds_w[128 * 64];
    int l0 = blockIdx.x * 128;
    int og0 = blockIdx.y * 128;
    int n = blockIdx.z;
    int mat = og0 >> 8;       // 0=q,1=k,2=v
    int om0 = og0 & 255;
    const void* W = (mat == 0) ? Wq : (mat == 1) ? Wk : Wv;
    const void* bias = (mat == 0) ? bq : (mat == 1) ? bk : bv;
    int mode = probe_mode(W);
    int tid = threadIdx.x, w = tid >> 6, lane = tid & 63;
    int quad = lane >> 4, l16 = lane & 15;
    const f16* xb = g_xbT + n * CHW;

    f32x4 acc[2][8];
#pragma unroll
    for (int a = 0; a < 2; a++)
#pragma unroll
        for (int b = 0; b < 8; b++) acc[a][b] = f32x4{0.f, 0.f, 0.f, 0.f};

    for (int ch = 0; ch < 4; ++ch) {
        int cc0 = ch * 64;
        f16x8 xs[4], wsr[4];
#pragma unroll
        for (int ti = 0; ti < 4; ++ti) {
            int s = (w * 4 + ti) * 64 + lane;
            int row = s >> 3, gp = s & 7;
            xs[ti] = *(const f16x8*)(xb + (l0 + row) * C_DIM + cc0 + gp * 8);
            f16x8 h;
            if (mode == 0) {
                u16x8 wv = *(const u16x8*)((const ushort_t*)W + (om0 + row) * C_DIM + cc0 + gp * 8);
#pragma unroll
                for (int e = 0; e < 8; e++) h[e] = sf16(bf2f(wv[e]));
            } else {
                const float* wf = (const float*)W + (om0 + row) * C_DIM + cc0 + gp * 8;
#pragma unroll
                for (int e = 0; e < 8; e++) h[e] = sf16(wf[e]);
            }
            wsr[ti] = h;
        }
        __syncthreads();
#pragma unroll
        for (int ti = 0; ti < 4; ++ti) {
            int s = (w * 4 + ti) * 64 + lane;
            int row = s >> 3, gp = s & 7;
            int pos = gp ^ (row & 7);
            *(f16x8*)(lds_x + (row * 8 + pos) * 8) = xs[ti];
            *(f16x8*)(lds_w + (row * 8 + pos) * 8) = wsr[ti];
        }
        __syncthreads();
#pragma unroll
        for (int ks = 0; ks < 2; ++ks) {
            f16x8 af[2];
#pragma unroll
            for (int mt = 0; mt < 2; ++mt) {
                int row = w * 32 + mt * 16 + l16;
                int g = ks * 4 + quad;
                int pos = g ^ (row & 7);
                af[mt] = *(const f16x8*)(lds_x + (row * 8 + pos) * 8);
            }
#pragma unroll
            for (int nt = 0; nt < 8; ++nt) {
                int rowo = nt * 16 + l16;
                int g = ks * 4 + quad;
                int pos = g ^ (rowo & 7);
                f16x8 bfv = *(const f16x8*)(lds_w + (rowo * 8 + pos) * 8);
                if (mat < 2) {
                    acc[0][nt] = __builtin_amdgcn_mfma_f32_16x16x32_f16(af[0], bfv, acc[0][nt], 0, 0, 0);
                    acc[1][nt] = __builtin_amdgcn_mfma_f32_16x16x32_f16(af[1], bfv, acc[1][nt], 0, 0, 0);
                } else {
                    acc[0][nt] = __builtin_amdgcn_mfma_f32_16x16x32_f16(bfv, af[0], acc[0][nt], 0, 0, 0);
                    acc[1][nt] = __builtin_amdgcn_mfma_f32_16x16x32_f16(bfv, af[1], acc[1][nt], 0, 0, 0);
                }
            }
        }
        __syncthreads();
    }

    auto loadb = [&](int i) -> float {
        return mode ? ((const float*)bias)[i] : bf2f(((const ushort_t*)bias)[i]);
    };
    if (mat < 2) {
        f16* T = ((mat == 0) ? g_q : g_k) + n * CHW;
        float bvv[8];
#pragma unroll
        for (int nt = 0; nt < 8; nt++) bvv[nt] = loadb(om0 + nt * 16 + l16);
#pragma unroll
        for (int mt = 0; mt < 2; mt++)
#pragma unroll
            for (int nt = 0; nt < 8; nt++)
#pragma unroll
                for (int r = 0; r < 4; r++) {
                    int l = l0 + w * 32 + mt * 16 + quad * 4 + r;
                    int o = om0 + nt * 16 + l16;
                    T[l * C_DIM + o] = sf16(acc[mt][nt][r] + bvv[nt]);
                }
    } else {
        f16* T = g_v + n * CHW;
#pragma unroll
        for (int mt = 0; mt < 2; mt++)
#pragma unroll
            for (int nt = 0; nt < 8; nt++)
#pragma unroll
                for (int r = 0; r < 4; r++) {
                    int o = om0 + nt * 16 + quad * 4 + r;
                    int l = l0 + w * 32 + mt * 16 + l16;
                    T[o * HW + l] = sf16(acc[mt][nt][r] + loadb(o));
                }
    }
}

// ---------------- kernel 3: flash attention, single barrier/iter ----------------
// K and V both double-buffered via global_load_lds (DMA). P-transpose through a
// shared per-wave region, mt-sequential (DS ops in-order per wave).
// LDS 69 KB -> 2 blocks/CU; VGPR capped 128 by __launch_bounds__(256,2).
__global__ __launch_bounds__(256, 2) void k_attn() {
    __shared__ __align__(16) char smem[70656];
    f16* kbuf = (f16*)smem;             // 2 x 8192 f16 (32 j x 32 granules, swizzled)
    f16* vbuf = (f16*)(smem + 32768);   // 2 x 8192 f16 (256 c x 4 granules, swizzled)
    f16* pb   = (f16*)(smem + 65536);   // 4 waves x 640 f16 (shared across mt)

    int bid = blockIdx.x;
    int x8 = bid & 7;
    int n = x8 >> 1, jhi = x8 & 1;
    int rest = bid >> 3;
    int jlo = rest & 1;
    int i0 = (rest >> 1) * 128;
    int jq = jhi * 2 + jlo;
    int tid = threadIdx.x, w = tid >> 6, lane = tid & 63;
    int quad = lane >> 4, l16 = lane & 15;

    const f16* Qb = g_q + n * CHW;
    const f16* Kb = g_k + n * CHW;
    const f16* Vb = g_v + n * CHW;
    f16* pw = pb + w * 640;

    int koff0[8], koff1[8], voff[16];
#pragma unroll
    for (int kk = 0; kk < 8; kk++) {
        int g2 = kk * 4 + quad;
        int pos = (g2 & 24) | ((g2 & 7) ^ (l16 & 7));
        koff0[kk] = (l16 * 32 + pos) * 8;
        koff1[kk] = ((16 + l16) * 32 + pos) * 8;
    }
#pragma unroll
    for (int ct = 0; ct < 16; ct++) {
        int c = ct * 16 + l16;
        voff[ct] = (c * 4 + (quad ^ ((c >> 1) & 3))) * 8;
    }

    f16x8 qf[2][8];
#pragma unroll
    for (int mt = 0; mt < 2; mt++) {
        const f16* qrow = Qb + (i0 + w * 32 + mt * 16 + l16) * C_DIM + quad * 8;
#pragma unroll
        for (int kk = 0; kk < 8; kk++)
            qf[mt][kk] = *(const f16x8*)(qrow + kk * 32);
    }

    f32x4 o_acc[2][16];
#pragma unroll
    for (int mt = 0; mt < 2; mt++)
#pragma unroll
        for (int i = 0; i < 16; i++) o_acc[mt][i] = f32x4{0.f, 0.f, 0.f, 0.f};
    float m_[2] = {-1e30f, -1e30f}, l_[2] = {0.f, 0.f};

    auto stageK = [&](int jt, int buf) {
#pragma unroll
        for (int s = 0; s < 4; ++s) {
            int idx = s * 256 + tid;
            int j = idx >> 5, gp = idx & 31;
            int gg = (gp & 24) | ((gp & 7) ^ (j & 7));
            gl2lds16(Kb + (jt * 32 + j) * C_DIM + gg * 8,
                     kbuf + (buf * 1024 + s * 256 + w * 64) * 8);
        }
    };
    auto stageV = [&](int jt, int buf) {
#pragma unroll
        for (int s = 0; s < 4; ++s) {
            int idx = s * 256 + tid;
            int c = idx >> 2, jp = idx & 3;
            int jg = jp ^ ((c >> 1) & 3);
            gl2lds16(Vb + c * HW + jt * 32 + jg * 8,
                     vbuf + (buf * 1024 + s * 256 + w * 64) * 8);
        }
    };

    int jt0 = jq * 32;
    stageK(jt0, 0);
    stageV(jt0, 0);
    __syncthreads();   // K(0), V(0) drained

    for (int it = 0; it < 32; ++it) {
        int buf = it & 1;
        if (it + 1 < 32) {
            stageK(jt0 + it + 1, buf ^ 1);   // DMA into other buffers, overlaps iter
            stageV(jt0 + it + 1, buf ^ 1);
        }

        const f16* kb = kbuf + buf * 8192;
        const f16* vb = vbuf + buf * 8192;

        // ---- S^T(it) = K Q^T ----
        f32x4 st[2][2];
        st[0][0] = f32x4{0.f,0.f,0.f,0.f}; st[0][1] = f32x4{0.f,0.f,0.f,0.f};
        st[1][0] = f32x4{0.f,0.f,0.f,0.f}; st[1][1] = f32x4{0.f,0.f,0.f,0.f};
#pragma unroll
        for (int kk = 0; kk < 8; kk++) {
            f16x8 kf0 = *(const f16x8*)(kb + koff0[kk]);
            f16x8 kf1 = *(const f16x8*)(kb + koff1[kk]);
            st[0][0] = __builtin_amdgcn_mfma_f32_16x16x32_f16(kf0, qf[0][kk], st[0][0], 0, 0, 0);
            st[0][1] = __builtin_amdgcn_mfma_f32_16x16x32_f16(kf1, qf[0][kk], st[0][1], 0, 0, 0);
            st[1][0] = __builtin_amdgcn_mfma_f32_16x16x32_f16(kf0, qf[1][kk], st[1][0], 0, 0, 0);
            st[1][1] = __builtin_amdgcn_mfma_f32_16x16x32_f16(kf1, qf[1][kk], st[1][1], 0, 0, 0);
        }

        // ---- per-lane online softmax (quantized max) ----
        float al[2];
        float pv0[2][4], pv1[2][4];
#pragma unroll
        for (int mt = 0; mt < 2; mt++) {
            float smax = fmaxf(fmaxf(fmaxf(st[mt][0][0], st[mt][0][1]), fmaxf(st[mt][0][2], st[mt][0][3])),
                               fmaxf(fmaxf(st[mt][1][0], st[mt][1][1]), fmaxf(st[mt][1][2], st[mt][1][3])));
            smax = fmaxf(smax, __shfl_xor(smax, 16, 64));
            smax = fmaxf(smax, __shfl_xor(smax, 32, 64));
            float mq = __builtin_ceilf(smax * 0.125f) * 8.f;
            float mn = fmaxf(m_[mt], mq);
            al[mt] = __builtin_amdgcn_exp2f((m_[mt] - mn) * L2E);
            float rs = 0.f;
#pragma unroll
            for (int r = 0; r < 4; r++) {
                pv0[mt][r] = __builtin_amdgcn_exp2f((st[mt][0][r] - mn) * L2E);
                pv1[mt][r] = __builtin_amdgcn_exp2f((st[mt][1][r] - mn) * L2E);
                rs += pv0[mt][r] + pv1[mt][r];
            }
            m_[mt] = mn;
            rs += __shfl_xor(rs, 16, 64);
            rs += __shfl_xor(rs, 32, 64);
            l_[mt] = l_[mt] * al[mt] + rs;
        }
        if (__any((al[0] < 1.0f) || (al[1] < 1.0f))) {
#pragma unroll
            for (int mt = 0; mt < 2; mt++)
#pragma unroll
                for (int t = 0; t < 16; t++) o_acc[mt][t] *= al[mt];
        }

        // ---- P^T via shared per-wave pb, mt-sequential (DS in-order per wave) ----
        f16* pm = pw + l16 * 40;
        *(f16x2*)(pm + quad * 4)          = f16x2{(f16)pv0[0][0], (f16)pv0[0][1]};
        *(f16x2*)(pm + quad * 4 + 2)      = f16x2{(f16)pv0[0][2], (f16)pv0[0][3]};
        *(f16x2*)(pm + 16 + quad * 4)     = f16x2{(f16)pv1[0][0], (f16)pv1[0][1]};
        *(f16x2*)(pm + 16 + quad * 4 + 2) = f16x2{(f16)pv1[0][2], (f16)pv1[0][3]};
        asm volatile("" ::: "memory");
        f16x8 pf0 = *(const f16x8*)(pw + l16 * 40 + quad * 8);
        asm volatile("" ::: "memory");   // pf0 reads ordered before mt1 overwrites
        *(f16x2*)(pm + quad * 4)          = f16x2{(f16)pv0[1][0], (f16)pv0[1][1]};
        *(f16x2*)(pm + quad * 4 + 2)      = f16x2{(f16)pv0[1][2], (f16)pv0[1][3]};
        *(f16x2*)(pm + 16 + quad * 4)     = f16x2{(f16)pv1[1][0], (f16)pv1[1][1]};
        *(f16x2*)(pm + 16 + quad * 4 + 2) = f16x2{(f16)pv1[1][2], (f16)pv1[1][3]};
        asm volatile("" ::: "memory");
        f16x8 pf1 = *(const f16x8*)(pw + l16 * 40 + quad * 8);

        // ---- O^T += V P^T ----
#pragma unroll
        for (int ct = 0; ct < 16; ++ct) {
            f16x8 vf = *(const f16x8*)(vb + voff[ct]);
            o_acc[0][ct] = __builtin_amdgcn_mfma_f32_16x16x32_f16(vf, pf0, o_acc[0][ct], 0, 0, 0);
            o_acc[1][ct] = __builtin_amdgcn_mfma_f32_16x16x32_f16(vf, pf1, o_acc[1][ct], 0, 0, 0);
        }

        __syncthreads();   // buf reads done (safe for it+2 overwrite); stage(it+1) drained
    }

    // ---- write partials: mt-adjacent stores so each quad covers a full 64B line ----
    int slot = jq * 4 + n;
    if (quad == 0) {
#pragma unroll
        for (int mt = 0; mt < 2; mt++) {
            int i = i0 + w * 32 + mt * 16 + l16;
            g_ml[(slot * 2 + 0) * HW + i] = m_[mt];
            g_ml[(slot * 2 + 1) * HW + i] = l_[mt];
        }
    }
    f16* ob = g_opart + slot * CHW;
    int ig0 = i0 + w * 32 + l16;
    float inv0 = (l_[0] > 1e-30f) ? 1.0f / l_[0] : 0.f;
    float inv1 = (l_[1] > 1e-30f) ? 1.0f / l_[1] : 0.f;
#pragma unroll
    for (int ct = 0; ct < 16; ct++)
#pragma unroll
        for (int r = 0; r < 4; r++) {
            int c = ct * 16 + quad * 4 + r;
            ob[c * HW + ig0]      = (f16)(o_acc[0][ct][r] * inv0);
            ob[c * HW + ig0 + 16] = (f16)(o_acc[1][ct][r] * inv1);
        }
}

// ---------------- kernel 4: merge 4 j-quarters + residual + store (8-wide) ----------------
__global__ __launch_bounds__(256) void k_combine(
    const void* __restrict__ xv, const void* __restrict__ gv, void* __restrict__ outv)
{
    int mode = probe_mode(xv);
    float gam = fin0(mode ? ((const float*)gv)[0] : bf2f(((const ushort_t*)gv)[0]));
    int n = blockIdx.y;
    int off = blockIdx.x * 2048 + threadIdx.x * 8;   // 8 consecutive i, same c
    int i = off & (HW - 1);

    u16x8 op[4];
    float ms[4][8], ls[4][8];
#pragma unroll
    for (int s = 0; s < 4; ++s) {
        int slot = s * 4 + n;
        op[s] = *(const u16x8*)((const ushort_t*)g_opart + slot * CHW + off);
        float4 mA = *(const float4*)&g_ml[(slot * 2 + 0) * HW + i];
        float4 mB = *(const float4*)&g_ml[(slot * 2 + 0) * HW + i + 4];
        float4 lA = *(const float4*)&g_ml[(slot * 2 + 1) * HW + i];
        float4 lB = *(const float4*)&g_ml[(slot * 2 + 1) * HW + i + 4];
        ms[s][0]=mA.x; ms[s][1]=mA.y; ms[s][2]=mA.z; ms[s][3]=mA.w;
        ms[s][4]=mB.x; ms[s][5]=mB.y; ms[s][6]=mB.z; ms[s][7]=mB.w;
        ls[s][0]=lA.x; ls[s][1]=lA.y; ls[s][2]=lA.z; ls[s][3]=lA.w;
        ls[s][4]=lB.x; ls[s][5]=lB.y; ls[s][6]=lB.z; ls[s][7]=lB.w;
    }

    float o[8];
#pragma unroll
    for (int e = 0; e < 8; ++e) {
        float m = fmaxf(fmaxf(ms[0][e], ms[1][e]), fmaxf(ms[2][e], ms[3][e]));
        float num = 0.f, den = 0.f;
#pragma unroll
        for (int s = 0; s < 4; ++s) {
            float wgt = __builtin_amdgcn_exp2f((ms[s][e] - m) * L2E) * ls[s][e];
            union { ushort_t u; f16 h; } cv; cv.u = (ushort_t)op[s][e];
            num += wgt * (float)cv.h;
            den += wgt;
        }
        o[e] = (den > 1e-30f) ? num / den : 0.f;
    }

    if (mode == 0) {
        u16x8 xp = *(const u16x8*)((const ushort_t*)xv + n * CHW + off);
        u16x8 res;
#pragma unroll
        for (int e = 0; e < 8; ++e)
            res[e] = f2bf(fin0(bf2f((ushort_t)xp[e]) + gam * o[e]));
        *(u16x8*)((ushort_t*)outv + n * CHW + off) = res;
    } else {
        const float* xb = (const float*)xv + n * CHW + off;
        float* outb = (float*)outv + n * CHW + off;
        float4 xA = *(const float4*)xb;
        float4 xB = *(const float4*)(xb + 4);
        float4 rA, rB;
        rA.x = fin0(xA.x + gam * o[0]); rA.y = fin0(xA.y + gam * o[1]);
        rA.z = fin0(xA.z + gam * o[2]); rA.w = fin0(xA.w + gam * o[3]);
        rB.x = fin0(xB.x + gam * o[4]); rB.y = fin0(xB.y + gam * o[5]);
        rB.z = fin0(xB.z + gam * o[6]); rB.w = fin0(xB.w + gam * o[7]);
        *(float4*)outb = rA;
        *(float4*)(outb + 4) = rB;
    }
}

extern "C" void kernel_launch(void* const* d_in, const int* in_sizes, int n_in,
                              void* d_out, int out_size, void* d_ws, size_t ws_size,
                              hipStream_t stream) {
    (void)d_ws; (void)ws_size;
    bool ok = (n_in == 8) &&
              in_sizes[0] == 4 * CHW &&
              in_sizes[1] == C_DIM * C_DIM && in_sizes[2] == C_DIM &&
              in_sizes[3] == C_DIM * C_DIM && in_sizes[4] == C_DIM &&
              in_sizes[5] == C_DIM * C_DIM && in_sizes[6] == C_DIM &&
              in_sizes[7] == 1 && out_size == 4 * CHW;
    if (!ok) {
        hipLaunchKernelGGL(k_sentinel, dim3((out_size + 255) / 256), dim3(256), 0, stream,
                           (ushort_t*)d_out, out_size);
        return;
    }
    hipLaunchKernelGGL(k_transpose, dim3(64, 4, 4), dim3(256), 0, stream, d_in[0]);
    hipLaunchKernelGGL(k_proj, dim3(32, 6, 4), dim3(256), 0, stream,
                       d_in[1], d_in[2], d_in[3], d_in[4], d_in[5], d_in[6]);
    hipLaunchKernelGGL(k_attn, dim3(512), dim3(256), 0, stream);
    hipLaunchKernelGGL(k_combine, dim3(CHW / 2048, 4), dim3(256), 0, stream,
                       d_in[0], d_in[7], d_out);
}